// Round 3
// baseline (244.789 us; speedup 1.0000x reference)
//
#include <hip/hip_runtime.h>
#include <hip/hip_cooperative_groups.h>

namespace cg = cooperative_groups;

typedef unsigned short ushort;
typedef unsigned int uint;
typedef unsigned char uchar;
typedef __attribute__((ext_vector_type(8))) int intx8;
typedef __attribute__((ext_vector_type(16))) float floatx16;

// Problem constants
#define T_STEPS 100
#define BATCH   32
#define NIN     1024
#define NOUT    512

// K layout: k = b*SEG + t, t padded 100 -> 112 (KPAD = 3584 = 56 x 64, so the
// MX-scaled 32x32x64 MFMA tiles K exactly). Operands fp8 e4m3, [rows][K],
// row stride 3648 B (64B-aligned rows, 14.25 x 256B rotates L2 channels).
#define SEG      112
#define KPAD     (BATCH * SEG)         // 3584
#define KSTRIDEB 3648
#define KS       8
#define KCHUNK   (KPAD / KS)           // 448 -> 7 K-steps of 64 per block

#define LR_LTP  (1e-4f)
#define LR_LTD  (-1e-4f)
#define INV_B   (1.0f / 32.0f)
#define DECAY   0.951229424500714f     // exp(-1/20)
#define D28     0.246596963941607f     // exp(-28/20)
#define TCH     28                     // t-chunk per thread
#define NCHUNK  4

// Output layout (floats): [delta_w | pre_tr_final | post_tr_final]
#define OFF_PRE  (NOUT * NIN)
#define OFF_POST (OFF_PRE + BATCH * NIN)

// Workspace (bytes): 4 fp8 operands, then bf16 Spart slabs
#define B_PRST  0
#define B_PRTT  ((size_t)NIN * KSTRIDEB)
#define B_POST  ((size_t)2 * NIN * KSTRIDEB)
#define B_POTT  ((size_t)2 * NIN * KSTRIDEB + (size_t)NOUT * KSTRIDEB)
#define B_END   ((size_t)2 * (NIN + NOUT) * KSTRIDEB)
#define SLABU   (NOUT * NIN + 128)     // bf16 slab stride (odd 256B multiple)

#define GRID    512                    // 2 blocks/CU, all co-resident

// NOTE (hard-won, prior session): no device-scope atomic storms / manual
// threadfence reductions in hot loops (5-10x regressions). This round fuses
// the 3 dispatches into ONE cooperative kernel with grid.sync() between
// phases — the sanctioned grid-wide barrier — to attack the per-dispatch
// fixed overhead that rounds 0-2 showed dominating (large per-kernel work
// changes moved dur_us by only ~2 us each).

static __device__ __forceinline__ uint pk4_fp8(float a, float b, float c, float d) {
    uint v = 0;
    v = __builtin_amdgcn_cvt_pk_fp8_f32(a, b, v, false);
    v = __builtin_amdgcn_cvt_pk_fp8_f32(c, d, v, true);
    return v;
}

static __device__ __forceinline__ ushort f2bf(float f) {
    union { float f; unsigned int u; } v; v.f = f;
    unsigned int r = (v.u + 0x7FFFu + ((v.u >> 16) & 1u)) >> 16;   // RNE
    return (ushort)r;
}

static __device__ __forceinline__ intx8 ld32(const uchar* p) {
    const uint4 lo = *(const uint4*)p;
    const uint4 hv = *(const uint4*)(p + 16);
    intx8 r;
    r[0] = (int)lo.x; r[1] = (int)lo.y; r[2] = (int)lo.z; r[3] = (int)lo.w;
    r[4] = (int)hv.x; r[5] = (int)hv.y; r[6] = (int)hv.z; r[7] = (int)hv.w;
    return r;
}

// ---------------------------------------------------------------------------
// Phase A body (verbatim round-0/2 logic, blockIdx -> vbid).
// Block = 64 chains x 4 t-chunks of 28. Split scan with exp(-28/20) carry
// fixup; fp8-packed results staged in LDS rows of 33 words; cooperative
// coalesced 16B write-out.
// ---------------------------------------------------------------------------
static __device__ __forceinline__ void phaseA(
    int vbid, uint* Ls, uint* Lt, float (*Eend)[64],
    const float* __restrict__ pre_s, const float* __restrict__ post_s,
    const float* __restrict__ pre_tr0, const float* __restrict__ post_tr0,
    uchar* __restrict__ pre_s_t, uchar* __restrict__ pre_tr_t,
    uchar* __restrict__ post_s_t, uchar* __restrict__ post_tr_t,
    float* __restrict__ out)
{
    const int chain = threadIdx.x & 63;
    const int c     = threadIdx.x >> 6;     // t-chunk, wave-uniform
    const int g     = vbid * 64 + chain;

    const float* src; const float* init;
    int id, stride, outoff;
    if (g < BATCH * NIN) {
        src = pre_s;  init = pre_tr0;
        id = g;               stride = BATCH * NIN;  outoff = OFF_PRE;
    } else {
        src = post_s; init = post_tr0;
        id = g - BATCH * NIN; stride = BATCH * NOUT; outoff = OFF_POST;
    }

    const int t0 = c * TCH;
    float x[TCH];
    #pragma unroll
    for (int m = 0; m < TCH; ++m)
        x[m] = (t0 + m < T_STEPS) ? src[(size_t)(t0 + m) * stride + id] : 0.f;

    // pack spikes to fp8 before the scan overwrites x[]
    uint sp[7];
    #pragma unroll
    for (int j = 0; j < 7; ++j)
        sp[j] = pk4_fp8(x[4*j], x[4*j+1], x[4*j+2], x[4*j+3]);

    // local scan (zero initial condition)
    float e = 0.f;
    #pragma unroll
    for (int m = 0; m < TCH; ++m) { e = e * DECAY + x[m]; x[m] = e; }
    Eend[c][chain] = e;
    __syncthreads();

    // carry into chunk c
    float C = init[id];
    for (int cc = 0; cc < c; ++cc) C = C * D28 + Eend[cc][chain];
    float p = C * DECAY;
    #pragma unroll
    for (int m = 0; m < TCH; ++m) { x[m] += p; p *= DECAY; }

    if (c == NCHUNK - 1) out[outoff + id] = x[15];   // t = 84 + 15 = 99

    // stage packed fp8 into LDS
    #pragma unroll
    for (int j = 0; j < 7; ++j) {
        const uint tj = pk4_fp8(x[4*j], x[4*j+1], x[4*j+2], x[4*j+3]);
        Ls[chain * 33 + c * 7 + j] = sp[j];
        Lt[chain * 33 + c * 7 + j] = tj;
    }
    __syncthreads();

    // cooperative coalesced write-out: 2 ops x 64 rows x 7 16B-chunks = 896
    const int id0 = vbid * 64;
    uchar *dS, *dT; int b0, ch0;
    if (id0 < BATCH * NIN) {
        b0 = id0 >> 10; ch0 = id0 & 1023; dS = pre_s_t;  dT = pre_tr_t;
    } else {
        const int idq = id0 - BATCH * NIN;
        b0 = idq >> 9;  ch0 = idq & 511;  dS = post_s_t; dT = post_tr_t;
    }
    #pragma unroll
    for (int j = 0; j < 4; ++j) {
        const int q = threadIdx.x + 256 * j;
        if (q < 896) {
            const int op = q >= 448;
            const int qq = q - op * 448;
            const int r  = qq / 7;
            const int cc = qq - r * 7;
            const uint* l = (op ? Lt : Ls) + r * 33 + cc * 4;
            const uint4 v = make_uint4(l[0], l[1], l[2], l[3]);
            uchar* gd = (op ? dT : dS) + (size_t)(ch0 + r) * KSTRIDEB + b0 * SEG + cc * 16;
            *(uint4*)gd = v;
        }
    }
}

// ---------------------------------------------------------------------------
// Fused kernel: A (trace+transpose, 768 vblocks folded 2:1) -> grid.sync ->
// B (dual MX-fp8 GEMM, no LDS/no barriers, kz = bid&7 XCD ownership) ->
// grid.sync -> C (slab reduction, 4 elems/thread).
// ---------------------------------------------------------------------------
__global__ __launch_bounds__(256, 2) void stdp_fused(
    const float* __restrict__ pre_s, const float* __restrict__ post_s,
    const float* __restrict__ pre_tr0, const float* __restrict__ post_tr0,
    const float* __restrict__ wmat,
    uchar* __restrict__ pre_s_t, uchar* __restrict__ pre_tr_t,
    uchar* __restrict__ post_s_t, uchar* __restrict__ post_tr_t,
    ushort* __restrict__ Spart, float* __restrict__ out)
{
    __shared__ uint Ls[64 * 33];
    __shared__ uint Lt[64 * 33];
    __shared__ float Eend[NCHUNK][64];

    // ---- Phase A: 768 virtual blocks on 512 real blocks (uniform per block)
    phaseA(blockIdx.x, Ls, Lt, Eend, pre_s, post_s, pre_tr0, post_tr0,
           pre_s_t, pre_tr_t, post_s_t, post_tr_t, out);
    if (blockIdx.x < 256)
        phaseA(blockIdx.x + GRID, Ls, Lt, Eend, pre_s, post_s, pre_tr0, post_tr0,
               pre_s_t, pre_tr_t, post_s_t, post_tr_t, out);

    cg::this_grid().sync();

    // ---- Phase B: dual MX-fp8 GEMM, tile 128(o) x 64(i), KS=8 K-split.
    {
        const int bid = blockIdx.x;
        const int kz = bid & 7;            // K-slab == XCD under round-robin
        const int iy = (bid >> 3) & 15;
        const int oz = bid >> 7;
        const int i0 = iy * 64;
        const int o0 = oz * 128;
        const int k0 = kz * KCHUNK;

        const int tid  = threadIdx.x;
        const int w    = tid >> 6;
        const int lane = tid & 63;
        const int wm   = w & 1;            // o-half (64 rows)
        const int wn   = w >> 1;           // i-half (32 cols)
        const int l32  = lane & 31;
        const int hi   = lane >> 5;

        floatx16 accP[2], accD[2];
        #pragma unroll
        for (int mt = 0; mt < 2; ++mt)
            #pragma unroll
            for (int r = 0; r < 16; ++r) { accP[mt][r] = 0.f; accD[mt][r] = 0.f; }

        const size_t aBase = (size_t)(o0 + wm * 64 + l32) * KSTRIDEB;
        const size_t bBase = (size_t)(i0 + wn * 32 + l32) * KSTRIDEB;

        for (int kb = k0; kb < k0 + KCHUNK; kb += 64) {
            const int ko = kb + (hi << 5);
            intx8 aP[2], aD[2], bP, bD;
            #pragma unroll
            for (int mt = 0; mt < 2; ++mt) {
                const size_t off = aBase + (size_t)(mt * 32) * KSTRIDEB + ko;
                aP[mt] = ld32(post_s_t  + off);
                aD[mt] = ld32(post_tr_t + off);
            }
            {
                const size_t off = bBase + ko;
                bP = ld32(pre_tr_t + off);
                bD = ld32(pre_s_t  + off);
            }
            #pragma unroll
            for (int mt = 0; mt < 2; ++mt) {
                accP[mt] = __builtin_amdgcn_mfma_scale_f32_32x32x64_f8f6f4(
                    aP[mt], bP, accP[mt], 0, 0, 0, 127, 0, 127);
                accD[mt] = __builtin_amdgcn_mfma_scale_f32_32x32x64_f8f6f4(
                    aD[mt], bD, accD[mt], 0, 0, 0, 127, 0, 127);
            }
        }

        // epilogue: 32x32 C/D layout col = lane&31 (i), row = (r&3)+8*(r>>2)+4*hi
        ushort* Sz = Spart + (size_t)kz * SLABU;
        const float c1 = LR_LTP * INV_B;
        const float c2 = LR_LTD * INV_B;
        #pragma unroll
        for (int mt = 0; mt < 2; ++mt) {
            const int ob = o0 + wm * 64 + mt * 32 + hi * 4;
            const int i  = i0 + wn * 32 + l32;
            #pragma unroll
            for (int r = 0; r < 16; ++r) {
                const int o = ob + (r & 3) + 8 * (r >> 2);
                const size_t idx = (size_t)o * NIN + i;
                const float wv = wmat[idx];
                const float v = c1 * (1.0f - wv) * accP[mt][r]
                              + c2 * wv          * accD[mt][r];
                Sz[idx] = f2bf(v);
            }
        }
    }

    cg::this_grid().sync();

    // ---- Phase C: sum KS bf16 slabs -> fp32 dw. 4 elements per thread.
    {
        const int j4 = blockIdx.x * 256 + threadIdx.x;   // 4-elem group
        float s[4] = {0.f, 0.f, 0.f, 0.f};
        #pragma unroll
        for (int z = 0; z < KS; ++z) {
            const uint2 v = *(const uint2*)(Spart + (size_t)z * SLABU + (size_t)j4 * 4);
            const uint u[2] = {v.x, v.y};
            #pragma unroll
            for (int q = 0; q < 2; ++q) {
                union { uint u; float f; } lo, hi;
                lo.u = u[q] << 16;
                hi.u = u[q] & 0xFFFF0000u;
                s[2 * q]     += lo.f;
                s[2 * q + 1] += hi.f;
            }
        }
        *(float4*)(out + (size_t)j4 * 4) = make_float4(s[0], s[1], s[2], s[3]);
    }
}

extern "C" void kernel_launch(void* const* d_in, const int* in_sizes, int n_in,
                              void* d_out, int out_size, void* d_ws, size_t ws_size,
                              hipStream_t stream) {
    const float* weight   = (const float*)d_in[0];
    const float* pre_s    = (const float*)d_in[1];
    const float* post_s   = (const float*)d_in[2];
    const float* pre_tr0  = (const float*)d_in[3];
    const float* post_tr0 = (const float*)d_in[4];
    float* out = (float*)d_out;

    uchar* wsb = (uchar*)d_ws;
    uchar* pre_s_t   = wsb + B_PRST;
    uchar* pre_tr_t  = wsb + B_PRTT;
    uchar* post_s_t  = wsb + B_POST;
    uchar* post_tr_t = wsb + B_POTT;
    ushort* Spart    = (ushort*)(wsb + B_END);

    void* args[] = {
        (void*)&pre_s, (void*)&post_s, (void*)&pre_tr0, (void*)&post_tr0,
        (void*)&weight,
        (void*)&pre_s_t, (void*)&pre_tr_t, (void*)&post_s_t, (void*)&post_tr_t,
        (void*)&Spart, (void*)&out
    };
    hipLaunchCooperativeKernel((const void*)stdp_fused, dim3(GRID), dim3(256),
                               args, 0, stream);
}

// Round 4
// 104.358 us; speedup vs baseline: 2.3457x; 2.3457x over previous
//
#include <hip/hip_runtime.h>

typedef unsigned short ushort;
typedef unsigned int uint;
typedef unsigned char uchar;
typedef __attribute__((ext_vector_type(8))) int intx8;
typedef __attribute__((ext_vector_type(16))) float floatx16;

// Problem constants
#define T_STEPS 100
#define BATCH   32
#define NIN     1024
#define NOUT    512

// K layout: k = b*SEG + t, t padded 100 -> 112 (KPAD = 3584 = 56 x 64, so the
// MX-scaled 32x32x64 MFMA tiles K exactly). Operands fp8 e4m3, [rows][K],
// row stride 3648 B (64B-aligned rows, 14.25 x 256B rotates L2 channels).
#define SEG      112
#define KPAD     (BATCH * SEG)         // 3584
#define KSTRIDEB 3648

#define LR_LTP  (1e-4f)
#define LR_LTD  (-1e-4f)
#define INV_B   (1.0f / 32.0f)
#define DECAY   0.951229424500714f     // exp(-1/20)
#define D28     0.246596963941607f     // exp(-28/20)
#define TCH     28                     // t-chunk per thread
#define NCHUNK  4

// Output layout (floats): [delta_w | pre_tr_final | post_tr_final]
#define OFF_PRE  (NOUT * NIN)
#define OFF_POST (OFF_PRE + BATCH * NIN)

// Workspace (bytes): 4 fp8 operands only (no partial slabs anymore)
#define B_PRST  0
#define B_PRTT  ((size_t)NIN * KSTRIDEB)
#define B_POST  ((size_t)2 * NIN * KSTRIDEB)
#define B_POTT  ((size_t)2 * NIN * KSTRIDEB + (size_t)NOUT * KSTRIDEB)

// NOTE (hard-won, prior session + round 3): NO cross-block synchronization of
// any kind in the hot path on this chip —
//   - device-scope atomic storms / __threadfence reductions: 5-10x regression
//   - cg::this_grid().sync() (cooperative launch): ~60-70 us PER SYNC at 512
//     blocks (round 3 measured the fused kernel at 157 us with <10 us of
//     actual pipe work; MfmaUtil 0.9%, VALUBusy 2.8%). grid.sync is a
//     device-scope fence + single-cacheline spin across 8 non-coherent-L2
//     XCDs. Never again.
// Structure of record: independent dispatches, dependencies carried through
// global memory only.
//
// NOTE (round 4): kernel C and the bf16 Spart round-trip are deleted. Kernel
// B computes FULL K (56 steps) per output tile and writes fp32 dw directly
// (fused w-combine). 2 dispatches total. B keeps the round-1/2 barrier-free
// direct-gather form: the MX 32x32x64 fragment ("row = lane&31, 32 contiguous
// K bytes at (lane>>5)*32") matches the [row][K] fp8 storage exactly, so
// fragments load straight from global (L2/LLC-resident), zero LDS, zero
// __syncthreads in the K loop.

static __device__ __forceinline__ uint pk4_fp8(float a, float b, float c, float d) {
    uint v = 0;
    v = __builtin_amdgcn_cvt_pk_fp8_f32(a, b, v, false);   // low 16 bits
    v = __builtin_amdgcn_cvt_pk_fp8_f32(c, d, v, true);    // high 16 bits
    return v;
}

static __device__ __forceinline__ intx8 ld32(const uchar* p) {
    const uint4 lo = *(const uint4*)p;
    const uint4 hv = *(const uint4*)(p + 16);
    intx8 r;
    r[0] = (int)lo.x; r[1] = (int)lo.y; r[2] = (int)lo.z; r[3] = (int)lo.w;
    r[4] = (int)hv.x; r[5] = (int)hv.y; r[6] = (int)hv.z; r[7] = (int)hv.w;
    return r;
}

// ---------------------------------------------------------------------------
// Kernel A: trace recurrence fused with transpose, fp8 e4m3 outputs.
// Block = 64 chains x 4 t-chunks of 28 (t >= 100: spikes zero-padded).
// Split scan with exp(-28/20) carry fixup. fp8-packed results staged in LDS
// rows of 33 words, then written out cooperatively as 16B chunks.
// (verbatim round-0/2 version: verified absmax 2^-10)
// ---------------------------------------------------------------------------
__global__ __launch_bounds__(256) void stdp_traces_t(
    const float* __restrict__ pre_s,    // [T,B,NIN]
    const float* __restrict__ post_s,   // [T,B,NOUT]
    const float* __restrict__ pre_tr0,  // [B,NIN]
    const float* __restrict__ post_tr0, // [B,NOUT]
    uchar* __restrict__ pre_s_t, uchar* __restrict__ pre_tr_t,
    uchar* __restrict__ post_s_t, uchar* __restrict__ post_tr_t,
    float* __restrict__ out)
{
    __shared__ uint Ls[64 * 33];   // packed fp8 spikes, 8.25 KB
    __shared__ uint Lt[64 * 33];   // packed fp8 traces
    __shared__ float Eend[NCHUNK][64];

    const int chain = threadIdx.x & 63;
    const int c     = threadIdx.x >> 6;     // t-chunk, wave-uniform
    const int g     = blockIdx.x * 64 + chain;

    const float* src; const float* init;
    int id, stride, outoff;
    if (g < BATCH * NIN) {
        src = pre_s;  init = pre_tr0;
        id = g;               stride = BATCH * NIN;  outoff = OFF_PRE;
    } else {
        src = post_s; init = post_tr0;
        id = g - BATCH * NIN; stride = BATCH * NOUT; outoff = OFF_POST;
    }

    const int t0 = c * TCH;
    float x[TCH];
    #pragma unroll
    for (int m = 0; m < TCH; ++m)
        x[m] = (t0 + m < T_STEPS) ? src[(size_t)(t0 + m) * stride + id] : 0.f;

    // pack spikes to fp8 before the scan overwrites x[]
    uint sp[7];
    #pragma unroll
    for (int j = 0; j < 7; ++j)
        sp[j] = pk4_fp8(x[4*j], x[4*j+1], x[4*j+2], x[4*j+3]);

    // local scan (zero initial condition)
    float e = 0.f;
    #pragma unroll
    for (int m = 0; m < TCH; ++m) { e = e * DECAY + x[m]; x[m] = e; }
    Eend[c][chain] = e;
    __syncthreads();

    // carry into chunk c
    float C = init[id];
    for (int cc = 0; cc < c; ++cc) C = C * D28 + Eend[cc][chain];
    float p = C * DECAY;
    #pragma unroll
    for (int m = 0; m < TCH; ++m) { x[m] += p; p *= DECAY; }

    if (c == NCHUNK - 1) out[outoff + id] = x[15];   // t = 84 + 15 = 99

    // stage packed fp8 into LDS
    #pragma unroll
    for (int j = 0; j < 7; ++j) {
        const uint tj = pk4_fp8(x[4*j], x[4*j+1], x[4*j+2], x[4*j+3]);
        Ls[chain * 33 + c * 7 + j] = sp[j];
        Lt[chain * 33 + c * 7 + j] = tj;
    }
    __syncthreads();

    // cooperative coalesced write-out: 2 ops x 64 rows x 7 16B-chunks = 896
    const int id0 = blockIdx.x * 64;
    uchar *dS, *dT; int b0, ch0;
    if (id0 < BATCH * NIN) {
        b0 = id0 >> 10; ch0 = id0 & 1023; dS = pre_s_t;  dT = pre_tr_t;
    } else {
        const int idq = id0 - BATCH * NIN;
        b0 = idq >> 9;  ch0 = idq & 511;  dS = post_s_t; dT = post_tr_t;
    }
    #pragma unroll
    for (int j = 0; j < 4; ++j) {
        const int q = threadIdx.x + 256 * j;
        if (q < 896) {
            const int op = q >= 448;
            const int qq = q - op * 448;
            const int r  = qq / 7;
            const int cc = qq - r * 7;
            const uint* l = (op ? Lt : Ls) + r * 33 + cc * 4;
            const uint4 v = make_uint4(l[0], l[1], l[2], l[3]);
            uchar* gd = (op ? dT : dS) + (size_t)(ch0 + r) * KSTRIDEB + b0 * SEG + cc * 16;
            *(uint4*)gd = v;
        }
    }
}

// ---------------------------------------------------------------------------
// Kernel B: dual MX-fp8 MFMA GEMM (mfma_scale 32x32x64, scale=1.0), FULL K
// (56 steps of 64, no K-split -> no partials, no finalize kernel).
// Block = 128 threads = 2 waves; block tile 32(o) x 64(i); each wave one
// 32x32 MFMA tile (wn = i-half). A-fragments shared by both waves -> L1 hits.
// Grid (NIN/64, NOUT/32) = (16,16) = 256 blocks = 1/CU, all CUs busy.
//   P[o,i] = sum_k post_s[k,o]*pre_tr[k,i]
//   D[o,i] = sum_k post_tr[k,o]*pre_s[k,i]
// Epilogue: dw[o,i] = c1*(1-w)*P + c2*w*D written fp32 directly to out.
// ---------------------------------------------------------------------------
__global__ __launch_bounds__(128) void stdp_gemm_dual(
    const uchar* __restrict__ post_s_t, const uchar* __restrict__ pre_tr_t,
    const uchar* __restrict__ post_tr_t, const uchar* __restrict__ pre_s_t,
    const float* __restrict__ wmat, float* __restrict__ out)
{
    const int i0 = blockIdx.x * 64;
    const int o0 = blockIdx.y * 32;

    const int tid  = threadIdx.x;
    const int wn   = tid >> 6;             // i-half (32 cols)
    const int lane = tid & 63;
    const int l32  = lane & 31;
    const int hi   = lane >> 5;

    floatx16 accP, accD;
    #pragma unroll
    for (int r = 0; r < 16; ++r) { accP[r] = 0.f; accD[r] = 0.f; }

    const size_t aBase = (size_t)(o0 + l32) * KSTRIDEB + (hi << 5);
    const size_t bBase = (size_t)(i0 + wn * 32 + l32) * KSTRIDEB + (hi << 5);

    for (int kb = 0; kb < KPAD; kb += 64) {
        const intx8 aP = ld32(post_s_t  + aBase + kb);
        const intx8 aD = ld32(post_tr_t + aBase + kb);
        const intx8 bP = ld32(pre_tr_t  + bBase + kb);
        const intx8 bD = ld32(pre_s_t   + bBase + kb);
        accP = __builtin_amdgcn_mfma_scale_f32_32x32x64_f8f6f4(
            aP, bP, accP, 0, 0, 0, 127, 0, 127);
        accD = __builtin_amdgcn_mfma_scale_f32_32x32x64_f8f6f4(
            aD, bD, accD, 0, 0, 0, 127, 0, 127);
    }

    // epilogue: 32x32 C/D layout col = lane&31 (i), row = (r&3)+8*(r>>2)+4*hi (o)
    const float c1 = LR_LTP * INV_B;
    const float c2 = LR_LTD * INV_B;
    const int i  = i0 + wn * 32 + l32;
    const int ob = o0 + hi * 4;
    #pragma unroll
    for (int r = 0; r < 16; ++r) {
        const int o = ob + (r & 3) + 8 * (r >> 2);
        const size_t idx = (size_t)o * NIN + i;
        const float wv = wmat[idx];
        out[idx] = c1 * (1.0f - wv) * accP[r] + c2 * wv * accD[r];
    }
}

extern "C" void kernel_launch(void* const* d_in, const int* in_sizes, int n_in,
                              void* d_out, int out_size, void* d_ws, size_t ws_size,
                              hipStream_t stream) {
    const float* weight   = (const float*)d_in[0];
    const float* pre_s    = (const float*)d_in[1];
    const float* post_s   = (const float*)d_in[2];
    const float* pre_tr0  = (const float*)d_in[3];
    const float* post_tr0 = (const float*)d_in[4];
    float* out = (float*)d_out;

    uchar* wsb = (uchar*)d_ws;
    uchar* pre_s_t   = wsb + B_PRST;
    uchar* pre_tr_t  = wsb + B_PRTT;
    uchar* post_s_t  = wsb + B_POST;
    uchar* post_tr_t = wsb + B_POTT;

    stdp_traces_t<<<dim3(BATCH * (NIN + NOUT) / 64), dim3(256), 0, stream>>>(
        pre_s, post_s, pre_tr0, post_tr0,
        pre_s_t, pre_tr_t, post_s_t, post_tr_t, out);

    stdp_gemm_dual<<<dim3(NIN / 64, NOUT / 32), dim3(128), 0, stream>>>(
        post_s_t, pre_tr_t, post_tr_t, pre_s_t, weight, out);
}

// Round 5
// 101.917 us; speedup vs baseline: 2.4019x; 1.0240x over previous
//
#include <hip/hip_runtime.h>

typedef unsigned short ushort;
typedef unsigned int uint;
typedef unsigned char uchar;
typedef __attribute__((ext_vector_type(8))) int intx8;
typedef __attribute__((ext_vector_type(16))) float floatx16;

// Problem constants
#define T_STEPS 100
#define BATCH   32
#define NIN     1024
#define NOUT    512

// K layout: k = b*SEG + t, t padded 100 -> 112 (KPAD = 3584 = 56 x 64, so the
// MX-scaled 32x32x64 MFMA tiles K exactly). Operands fp8 e4m3, [rows][K],
// row stride 3648 B (64B-aligned rows, 14.25 x 256B rotates L2 channels).
#define SEG      112
#define KPAD     (BATCH * SEG)         // 3584
#define KSTRIDEB 3648
#define KQ       (KPAD / 4)            // 896 = per-wave K slice, 14 steps of 64

#define LR_LTP  (1e-4f)
#define LR_LTD  (-1e-4f)
#define INV_B   (1.0f / 32.0f)
#define DECAY   0.951229424500714f     // exp(-1/20)
#define D28     0.246596963941607f     // exp(-28/20)
#define TCH     28                     // t-chunk per thread
#define NCHUNK  4

// Output layout (floats): [delta_w | pre_tr_final | post_tr_final]
#define OFF_PRE  (NOUT * NIN)
#define OFF_POST (OFF_PRE + BATCH * NIN)

// Workspace (bytes): 4 fp8 operands only (no partial slabs)
#define B_PRST  0
#define B_PRTT  ((size_t)NIN * KSTRIDEB)
#define B_POST  ((size_t)2 * NIN * KSTRIDEB)
#define B_POTT  ((size_t)2 * NIN * KSTRIDEB + (size_t)NOUT * KSTRIDEB)

// NOTE (hard-won, prior session + rounds 3-4): NO cross-block synchronization
// in the hot path on this chip —
//   - device-scope atomic storms / __threadfence reductions: 5-10x regression
//   - cg::this_grid().sync(): ~60-70 us PER SYNC at 512 blocks (round 3:
//     fused kernel 157 us with <10 us of pipe work). Never again.
//   - round 4: 128-thread blocks at 1 block/CU for the GEMM = 2 waves on 2
//     of 4 SIMDs -> latency-bound, +20 us. GEMM blocks must be 256 thr,
//     >= 2 blocks/CU.
// Structure of record: 2 independent dispatches (traces -> GEMM), deps via
// global memory; GEMM does full K per block, waves split K 4-way + LDS
// reduce (intra-block only).

static __device__ __forceinline__ uint pk4_fp8(float a, float b, float c, float d) {
    uint v = 0;
    v = __builtin_amdgcn_cvt_pk_fp8_f32(a, b, v, false);   // low 16 bits
    v = __builtin_amdgcn_cvt_pk_fp8_f32(c, d, v, true);    // high 16 bits
    return v;
}

static __device__ __forceinline__ intx8 ld32(const uchar* p) {
    const uint4 lo = *(const uint4*)p;
    const uint4 hv = *(const uint4*)(p + 16);
    intx8 r;
    r[0] = (int)lo.x; r[1] = (int)lo.y; r[2] = (int)lo.z; r[3] = (int)lo.w;
    r[4] = (int)hv.x; r[5] = (int)hv.y; r[6] = (int)hv.z; r[7] = (int)hv.w;
    return r;
}

// ---------------------------------------------------------------------------
// Kernel A: trace recurrence fused with transpose, fp8 e4m3 outputs.
// Block = 64 chains x 4 t-chunks of 28 (t >= 100: spikes zero-padded).
// Split scan with exp(-28/20) carry fixup. fp8-packed results staged in LDS
// rows of 33 words, then written out cooperatively as 16B chunks.
// (verbatim round-0/2 version: verified absmax 2^-10)
// ---------------------------------------------------------------------------
__global__ __launch_bounds__(256) void stdp_traces_t(
    const float* __restrict__ pre_s,    // [T,B,NIN]
    const float* __restrict__ post_s,   // [T,B,NOUT]
    const float* __restrict__ pre_tr0,  // [B,NIN]
    const float* __restrict__ post_tr0, // [B,NOUT]
    uchar* __restrict__ pre_s_t, uchar* __restrict__ pre_tr_t,
    uchar* __restrict__ post_s_t, uchar* __restrict__ post_tr_t,
    float* __restrict__ out)
{
    __shared__ uint Ls[64 * 33];   // packed fp8 spikes, 8.25 KB
    __shared__ uint Lt[64 * 33];   // packed fp8 traces
    __shared__ float Eend[NCHUNK][64];

    const int chain = threadIdx.x & 63;
    const int c     = threadIdx.x >> 6;     // t-chunk, wave-uniform
    const int g     = blockIdx.x * 64 + chain;

    const float* src; const float* init;
    int id, stride, outoff;
    if (g < BATCH * NIN) {
        src = pre_s;  init = pre_tr0;
        id = g;               stride = BATCH * NIN;  outoff = OFF_PRE;
    } else {
        src = post_s; init = post_tr0;
        id = g - BATCH * NIN; stride = BATCH * NOUT; outoff = OFF_POST;
    }

    const int t0 = c * TCH;
    float x[TCH];
    #pragma unroll
    for (int m = 0; m < TCH; ++m)
        x[m] = (t0 + m < T_STEPS) ? src[(size_t)(t0 + m) * stride + id] : 0.f;

    // pack spikes to fp8 before the scan overwrites x[]
    uint sp[7];
    #pragma unroll
    for (int j = 0; j < 7; ++j)
        sp[j] = pk4_fp8(x[4*j], x[4*j+1], x[4*j+2], x[4*j+3]);

    // local scan (zero initial condition)
    float e = 0.f;
    #pragma unroll
    for (int m = 0; m < TCH; ++m) { e = e * DECAY + x[m]; x[m] = e; }
    Eend[c][chain] = e;
    __syncthreads();

    // carry into chunk c
    float C = init[id];
    for (int cc = 0; cc < c; ++cc) C = C * D28 + Eend[cc][chain];
    float p = C * DECAY;
    #pragma unroll
    for (int m = 0; m < TCH; ++m) { x[m] += p; p *= DECAY; }

    if (c == NCHUNK - 1) out[outoff + id] = x[15];   // t = 84 + 15 = 99

    // stage packed fp8 into LDS
    #pragma unroll
    for (int j = 0; j < 7; ++j) {
        const uint tj = pk4_fp8(x[4*j], x[4*j+1], x[4*j+2], x[4*j+3]);
        Ls[chain * 33 + c * 7 + j] = sp[j];
        Lt[chain * 33 + c * 7 + j] = tj;
    }
    __syncthreads();

    // cooperative coalesced write-out: 2 ops x 64 rows x 7 16B-chunks = 896
    const int id0 = blockIdx.x * 64;
    uchar *dS, *dT; int b0, ch0;
    if (id0 < BATCH * NIN) {
        b0 = id0 >> 10; ch0 = id0 & 1023; dS = pre_s_t;  dT = pre_tr_t;
    } else {
        const int idq = id0 - BATCH * NIN;
        b0 = idq >> 9;  ch0 = idq & 511;  dS = post_s_t; dT = post_tr_t;
    }
    #pragma unroll
    for (int j = 0; j < 4; ++j) {
        const int q = threadIdx.x + 256 * j;
        if (q < 896) {
            const int op = q >= 448;
            const int qq = q - op * 448;
            const int r  = qq / 7;
            const int cc = qq - r * 7;
            const uint* l = (op ? Lt : Ls) + r * 33 + cc * 4;
            const uint4 v = make_uint4(l[0], l[1], l[2], l[3]);
            uchar* gd = (op ? dT : dS) + (size_t)(ch0 + r) * KSTRIDEB + b0 * SEG + cc * 16;
            *(uint4*)gd = v;
        }
    }
}

// ---------------------------------------------------------------------------
// Kernel B: dual MX-fp8 MFMA GEMM (mfma_scale 32x32x64, scale=1.0), FULL K,
// no inter-block partials. 512 blocks x 256 thr (2 blocks/CU, 8 waves/CU).
// Block tile 32(o) x 32(i); the 4 waves split K 4-way (896 each, 14 steps of
// 64), barrier-free direct-gather K-loop (fragment layout == storage layout),
// then one intra-block LDS reduction (lane-consecutive -> conflict-free) and
// the fused w-combine epilogue writes fp32 dw directly.
//   P[o,i] = sum_k post_s[k,o]*pre_tr[k,i]
//   D[o,i] = sum_k post_tr[k,o]*pre_s[k,i]
//   dw[o,i] = c1*(1-w)*P + c2*w*D
// XCD partition: xcd = bid&7 owns an 8x8 (o-tile x i-tile) region ->
// 256 A-rows + 256 B-rows (~3.7 MB) resident in that XCD's 4 MiB L2.
// ---------------------------------------------------------------------------
__global__ __launch_bounds__(256, 2) void stdp_gemm_dual(
    const uchar* __restrict__ post_s_t, const uchar* __restrict__ pre_tr_t,
    const uchar* __restrict__ post_tr_t, const uchar* __restrict__ pre_s_t,
    const float* __restrict__ wmat, float* __restrict__ out)
{
    __shared__ float red[4][2][16][64];   // 32 KB

    const int bid = blockIdx.x;
    const int xcd = bid & 7;
    const int l   = bid >> 3;
    const int ot  = (xcd & 1) * 8 + (l & 7);    // 0..15
    const int it  = (xcd >> 1) * 8 + (l >> 3);  // 0..31
    const int o0  = ot * 32;
    const int i0  = it * 32;

    const int w    = threadIdx.x >> 6;          // K-quarter
    const int lane = threadIdx.x & 63;
    const int l32  = lane & 31;
    const int hi   = lane >> 5;

    floatx16 accP, accD;
    #pragma unroll
    for (int r = 0; r < 16; ++r) { accP[r] = 0.f; accD[r] = 0.f; }

    const size_t aBase = (size_t)(o0 + l32) * KSTRIDEB + (hi << 5);
    const size_t bBase = (size_t)(i0 + l32) * KSTRIDEB + (hi << 5);
    const int k0 = w * KQ;

    #pragma unroll 2
    for (int kb = k0; kb < k0 + KQ; kb += 64) {
        const intx8 aP = ld32(post_s_t  + aBase + kb);
        const intx8 aD = ld32(post_tr_t + aBase + kb);
        const intx8 bP = ld32(pre_tr_t  + bBase + kb);
        const intx8 bD = ld32(pre_s_t   + bBase + kb);
        accP = __builtin_amdgcn_mfma_scale_f32_32x32x64_f8f6f4(
            aP, bP, accP, 0, 0, 0, 127, 0, 127);
        accD = __builtin_amdgcn_mfma_scale_f32_32x32x64_f8f6f4(
            aD, bD, accD, 0, 0, 0, 127, 0, 127);
    }

    // intra-block reduction over the 4 K-quarters (lane-consecutive LDS)
    #pragma unroll
    for (int r = 0; r < 16; ++r) {
        red[w][0][r][lane] = accP[r];
        red[w][1][r][lane] = accD[r];
    }
    __syncthreads();

    // epilogue: 32x32 C/D layout col = ln&31 (i), row = (r&3)+8*(r>>2)+4*(ln>>5)
    const float c1 = LR_LTP * INV_B;
    const float c2 = LR_LTD * INV_B;
    #pragma unroll
    for (int q = 0; q < 4; ++q) {
        const int e  = threadIdx.x + 256 * q;   // 0..1023 -> (r, ln)
        const int ln = e & 63;
        const int r  = e >> 6;
        const float sP = red[0][0][r][ln] + red[1][0][r][ln]
                       + red[2][0][r][ln] + red[3][0][r][ln];
        const float sD = red[0][1][r][ln] + red[1][1][r][ln]
                       + red[2][1][r][ln] + red[3][1][r][ln];
        const int o = o0 + (r & 3) + 8 * (r >> 2) + 4 * (ln >> 5);
        const int i = i0 + (ln & 31);
        const size_t idx = (size_t)o * NIN + i;
        const float wv = wmat[idx];
        out[idx] = c1 * (1.0f - wv) * sP + c2 * wv * sD;
    }
}

extern "C" void kernel_launch(void* const* d_in, const int* in_sizes, int n_in,
                              void* d_out, int out_size, void* d_ws, size_t ws_size,
                              hipStream_t stream) {
    const float* weight   = (const float*)d_in[0];
    const float* pre_s    = (const float*)d_in[1];
    const float* post_s   = (const float*)d_in[2];
    const float* pre_tr0  = (const float*)d_in[3];
    const float* post_tr0 = (const float*)d_in[4];
    float* out = (float*)d_out;

    uchar* wsb = (uchar*)d_ws;
    uchar* pre_s_t   = wsb + B_PRST;
    uchar* pre_tr_t  = wsb + B_PRTT;
    uchar* post_s_t  = wsb + B_POST;
    uchar* post_tr_t = wsb + B_POTT;

    stdp_traces_t<<<dim3(BATCH * (NIN + NOUT) / 64), dim3(256), 0, stream>>>(
        pre_s, post_s, pre_tr0, post_tr0,
        pre_s_t, pre_tr_t, post_s_t, post_tr_t, out);

    stdp_gemm_dual<<<dim3(512), dim3(256), 0, stream>>>(
        post_s_t, pre_tr_t, post_tr_t, pre_s_t, weight, out);
}

// Round 6
// 98.566 us; speedup vs baseline: 2.4835x; 1.0340x over previous
//
#include <hip/hip_runtime.h>

typedef unsigned short ushort;
typedef unsigned int uint;
typedef unsigned char uchar;
typedef __attribute__((ext_vector_type(8))) int intx8;
typedef __attribute__((ext_vector_type(16))) float floatx16;

// Problem constants
#define T_STEPS 100
#define BATCH   32
#define NIN     1024
#define NOUT    512

// K layout: k = b*SEG + t, t padded 100 -> 112 (KPAD = 3584 = 56 x 64, so the
// MX-scaled 32x32x64 MFMA tiles K exactly with no 128-pad waste).
// Operands stored fp8 e4m3, [rows][K], row stride 3648 B = 57 x 64B
// (64B-aligned rows, 14.25 x 256B rotates L2 channels).
#define SEG      112
#define KPAD     (BATCH * SEG)         // 3584 (GEMM K extent, bytes = elems)
#define KSTRIDEB 3648                  // row stride in bytes
#define KS       8
#define KCHUNK   (KPAD / KS)           // 448 -> 7 K-steps of 64 per block

#define LR_LTP  (1e-4f)
#define LR_LTD  (-1e-4f)
#define INV_B   (1.0f / 32.0f)
#define DECAY   0.951229424500714f     // exp(-1/20)
#define D28     0.246596963941607f     // exp(-28/20)
#define TCH     28                     // t-chunk per thread
#define NCHUNK  4

// Output layout (floats): [delta_w | pre_tr_final | post_tr_final]
#define OFF_PRE  (NOUT * NIN)
#define OFF_POST (OFF_PRE + BATCH * NIN)

// Workspace (bytes): 4 fp8 operands, then bf16 Spart slabs
#define B_PRST  0
#define B_PRTT  ((size_t)NIN * KSTRIDEB)
#define B_POST  ((size_t)2 * NIN * KSTRIDEB)
#define B_POTT  ((size_t)2 * NIN * KSTRIDEB + (size_t)NOUT * KSTRIDEB)
#define B_END   ((size_t)2 * (NIN + NOUT) * KSTRIDEB)   // 11,206,656 B (16-aligned)
// bf16 partial slab stride: NOUT*NIN + 128 ushorts = 1,048,832 B = 4097 x 256B
// (odd 256B multiple -> full L2 channel rotation across slabs)
#define SLABU   (NOUT * NIN + 128)

// ===========================================================================
// SESSION LEDGER (rounds 0-5) — this is the measured optimum configuration.
//
//   R0  3-dispatch, 16x16x32 fp8 MFMA, KS=16, LDS-staged:        103.8 us
//   R1  MX 32x32x64 direct-gather, SEG=128:                      100.5 us
//   R2  SEG=112, KS=8, z-major XCD grouping (THIS FILE):          98.3 us  <- best
//   R3  single cooperative kernel, 2x grid.sync():               244.8 us  (sync ~60-70us each)
//   R4  2-dispatch, B full-K @ 128thr/1 blk/CU:                  104.4 us  (latency-bound)
//   R5  2-dispatch, B full-K @ 512x256, LDS reduce:              101.9 us  (3x L2 traffic)
//
// Fixed-overhead model (calibrated by R3: dur 244.8 with 157 us of kernel):
//   ~44 us workspace poison fill (268 MB, visible in every rocprof top-5)
// + ~33 us output transfer + ~5 us launch overhead  =>  ~82 us floor.
// Kernel work here ~16 us (A ~5.5, B ~4, C ~2.5, gaps ~4), within ~2x of the
// pure byte-movement minimum. Every structural alternative measured worse.
//
// HARD CONSTRAINTS (measured, do not revisit):
//   - NO cross-block sync: device-atomic storms / threadfence reductions
//     (5-10x), cg::grid.sync (~60-70 us per sync at 512 blocks).
//   - GEMM needs >= 2 blocks/CU at 256 thr; 128-thr/1-blk-CU is latency-bound.
//   - Full-K-per-block at adequate occupancy forces small tiles -> 2.7x L2
//     traffic. K-split + bf16 partial slabs + tiny finalize is cheaper.
// ===========================================================================

static __device__ __forceinline__ uint pk4_fp8(float a, float b, float c, float d) {
    uint v = 0;
    v = __builtin_amdgcn_cvt_pk_fp8_f32(a, b, v, false);   // low 16 bits
    v = __builtin_amdgcn_cvt_pk_fp8_f32(c, d, v, true);    // high 16 bits
    return v;
}

static __device__ __forceinline__ ushort f2bf(float f) {
    union { float f; unsigned int u; } v; v.f = f;
    unsigned int r = (v.u + 0x7FFFu + ((v.u >> 16) & 1u)) >> 16;   // RNE
    return (ushort)r;
}

// ---------------------------------------------------------------------------
// Kernel A: trace recurrence fused with transpose, fp8 e4m3 outputs.
// Block = 64 chains x 4 t-chunks of 28 (t >= 100: spikes zero-padded).
// Split scan with exp(-28/20) carry fixup. fp8-packed results staged in LDS
// rows of 33 words, then written out cooperatively as 16B chunks.
// (verified absmax 2^-10)
// ---------------------------------------------------------------------------
__global__ __launch_bounds__(256) void stdp_traces_t(
    const float* __restrict__ pre_s,    // [T,B,NIN]
    const float* __restrict__ post_s,   // [T,B,NOUT]
    const float* __restrict__ pre_tr0,  // [B,NIN]
    const float* __restrict__ post_tr0, // [B,NOUT]
    uchar* __restrict__ pre_s_t, uchar* __restrict__ pre_tr_t,
    uchar* __restrict__ post_s_t, uchar* __restrict__ post_tr_t,
    float* __restrict__ out)
{
    __shared__ uint Ls[64 * 33];   // packed fp8 spikes, 8.25 KB
    __shared__ uint Lt[64 * 33];   // packed fp8 traces
    __shared__ float Eend[NCHUNK][64];

    const int chain = threadIdx.x & 63;
    const int c     = threadIdx.x >> 6;     // t-chunk, wave-uniform
    const int g     = blockIdx.x * 64 + chain;

    const float* src; const float* init;
    int id, stride, outoff;
    if (g < BATCH * NIN) {
        src = pre_s;  init = pre_tr0;
        id = g;               stride = BATCH * NIN;  outoff = OFF_PRE;
    } else {
        src = post_s; init = post_tr0;
        id = g - BATCH * NIN; stride = BATCH * NOUT; outoff = OFF_POST;
    }

    const int t0 = c * TCH;
    float x[TCH];
    #pragma unroll
    for (int m = 0; m < TCH; ++m)
        x[m] = (t0 + m < T_STEPS) ? src[(size_t)(t0 + m) * stride + id] : 0.f;

    // pack spikes to fp8 before the scan overwrites x[]
    uint sp[7];
    #pragma unroll
    for (int j = 0; j < 7; ++j)
        sp[j] = pk4_fp8(x[4*j], x[4*j+1], x[4*j+2], x[4*j+3]);

    // local scan (zero initial condition)
    float e = 0.f;
    #pragma unroll
    for (int m = 0; m < TCH; ++m) { e = e * DECAY + x[m]; x[m] = e; }
    Eend[c][chain] = e;
    __syncthreads();

    // carry into chunk c
    float C = init[id];
    for (int cc = 0; cc < c; ++cc) C = C * D28 + Eend[cc][chain];
    float p = C * DECAY;
    #pragma unroll
    for (int m = 0; m < TCH; ++m) { x[m] += p; p *= DECAY; }

    if (c == NCHUNK - 1) out[outoff + id] = x[15];   // t = 84 + 15 = 99

    // stage packed fp8 into LDS
    #pragma unroll
    for (int j = 0; j < 7; ++j) {
        const uint tj = pk4_fp8(x[4*j], x[4*j+1], x[4*j+2], x[4*j+3]);
        Ls[chain * 33 + c * 7 + j] = sp[j];
        Lt[chain * 33 + c * 7 + j] = tj;
    }
    __syncthreads();

    // cooperative coalesced write-out: 2 ops x 64 rows x 7 16B-chunks = 896
    const int id0 = blockIdx.x * 64;
    uchar *dS, *dT; int b0, ch0;
    if (id0 < BATCH * NIN) {
        b0 = id0 >> 10; ch0 = id0 & 1023; dS = pre_s_t;  dT = pre_tr_t;
    } else {
        const int idq = id0 - BATCH * NIN;
        b0 = idq >> 9;  ch0 = idq & 511;  dS = post_s_t; dT = post_tr_t;
    }
    #pragma unroll
    for (int j = 0; j < 4; ++j) {
        const int q = threadIdx.x + 256 * j;
        if (q < 896) {
            const int op = q >= 448;
            const int qq = q - op * 448;
            const int r  = qq / 7;
            const int cc = qq - r * 7;
            const uint* l = (op ? Lt : Ls) + r * 33 + cc * 4;
            const uint4 v = make_uint4(l[0], l[1], l[2], l[3]);
            uchar* gd = (op ? dT : dS) + (size_t)(ch0 + r) * KSTRIDEB + b0 * SEG + cc * 16;
            *(uint4*)gd = v;
        }
    }
}

// ---------------------------------------------------------------------------
// Kernel B: dual MX-fp8 MFMA GEMM (mfma_scale 32x32x64, scale=1.0), tile
// 128(o) x 64(i), 4 waves 2x2 (each wave 64x32 out), KS=8 K-split
// (512 blocks = 2/CU, 7 K-steps of 64). No LDS, no barriers: fragments
// loaded per-lane direct from global (row = lane&31, 32 contiguous K bytes
// at (lane>>5)*32 — matches storage).
//   P[o,i] = sum_k post_s[k,o]*pre_tr[k,i]
//   D[o,i] = sum_k post_tr[k,o]*pre_s[k,i]
// Epilogue pre-combines with w and stores BF16 partials:
//   Spart[z][o,i] = bf16( c1*(1-w)*P + c2*w*D )
// Grid (KS, 16, 4) z-major-in-x: linear id % 8 == kz -> each XCD owns one
// K-slab; its operand chunk, w working set and Spart slab stay in that L2.
// ---------------------------------------------------------------------------
static __device__ __forceinline__ intx8 ld32(const uchar* p) {
    const uint4 lo = *(const uint4*)p;
    const uint4 hv = *(const uint4*)(p + 16);
    intx8 r;
    r[0] = (int)lo.x; r[1] = (int)lo.y; r[2] = (int)lo.z; r[3] = (int)lo.w;
    r[4] = (int)hv.x; r[5] = (int)hv.y; r[6] = (int)hv.z; r[7] = (int)hv.w;
    return r;
}

__global__ __launch_bounds__(256, 2) void stdp_gemm_dual(
    const uchar* __restrict__ post_s_t, const uchar* __restrict__ pre_tr_t,
    const uchar* __restrict__ post_tr_t, const uchar* __restrict__ pre_s_t,
    const float* __restrict__ wmat, ushort* __restrict__ Spart)
{
    const int kz = blockIdx.x;             // K-slab -> XCD selector
    const int i0 = blockIdx.y * 64;
    const int o0 = blockIdx.z * 128;
    const int k0 = kz * KCHUNK;

    const int tid  = threadIdx.x;
    const int w    = tid >> 6;
    const int lane = tid & 63;
    const int wm   = w & 1;                // o-half (64 rows)
    const int wn   = w >> 1;               // i-half (32 cols)
    const int l32  = lane & 31;
    const int hi   = lane >> 5;

    floatx16 accP[2], accD[2];
    #pragma unroll
    for (int mt = 0; mt < 2; ++mt)
        #pragma unroll
        for (int r = 0; r < 16; ++r) { accP[mt][r] = 0.f; accD[mt][r] = 0.f; }

    const size_t aBase = (size_t)(o0 + wm * 64 + l32) * KSTRIDEB;
    const size_t bBase = (size_t)(i0 + wn * 32 + l32) * KSTRIDEB;

    for (int kb = k0; kb < k0 + KCHUNK; kb += 64) {
        const int ko = kb + (hi << 5);
        intx8 aP[2], aD[2], bP, bD;
        #pragma unroll
        for (int mt = 0; mt < 2; ++mt) {
            const size_t off = aBase + (size_t)(mt * 32) * KSTRIDEB + ko;
            aP[mt] = ld32(post_s_t  + off);
            aD[mt] = ld32(post_tr_t + off);
        }
        {
            const size_t off = bBase + ko;
            bP = ld32(pre_tr_t + off);
            bD = ld32(pre_s_t  + off);
        }
        #pragma unroll
        for (int mt = 0; mt < 2; ++mt) {
            accP[mt] = __builtin_amdgcn_mfma_scale_f32_32x32x64_f8f6f4(
                aP[mt], bP, accP[mt], 0, 0, 0, 127, 0, 127);
            accD[mt] = __builtin_amdgcn_mfma_scale_f32_32x32x64_f8f6f4(
                aD[mt], bD, accD[mt], 0, 0, 0, 127, 0, 127);
        }
    }

    // epilogue: 32x32 C/D layout col = lane&31 (i), row = (r&3)+8*(r>>2)+4*hi (o)
    ushort* Sz = Spart + (size_t)kz * SLABU;
    const float c1 = LR_LTP * INV_B;
    const float c2 = LR_LTD * INV_B;
    #pragma unroll
    for (int mt = 0; mt < 2; ++mt) {
        const int ob = o0 + wm * 64 + mt * 32 + hi * 4;
        const int i  = i0 + wn * 32 + l32;
        #pragma unroll
        for (int r = 0; r < 16; ++r) {
            const int o = ob + (r & 3) + 8 * (r >> 2);
            const size_t idx = (size_t)o * NIN + i;
            const float wv = wmat[idx];
            const float v = c1 * (1.0f - wv) * accP[mt][r]
                          + c2 * wv          * accD[mt][r];
            Sz[idx] = f2bf(v);
        }
    }
}

// ---------------------------------------------------------------------------
// Kernel C: sum the KS bf16 slabs -> fp32 dw. One thread per 8 outputs
// (16B slab loads), fp32 accumulation via bit-unpack.
// 512 blocks x 128 threads (2 blocks/CU) to cover the 8-load latency chains.
// ---------------------------------------------------------------------------
__global__ __launch_bounds__(128) void stdp_finalize(
    const ushort* __restrict__ Spart, float* __restrict__ out)
{
    const int j = blockIdx.x * blockDim.x + threadIdx.x;   // 8-element group
    float s[8] = {0.f, 0.f, 0.f, 0.f, 0.f, 0.f, 0.f, 0.f};
    #pragma unroll
    for (int z = 0; z < KS; ++z) {
        const uint4 v = *(const uint4*)(Spart + (size_t)z * SLABU + (size_t)j * 8);
        const uint u[4] = {v.x, v.y, v.z, v.w};
        #pragma unroll
        for (int q = 0; q < 4; ++q) {
            union { uint u; float f; } lo, hi;
            lo.u = u[q] << 16;
            hi.u = u[q] & 0xFFFF0000u;
            s[2 * q]     += lo.f;
            s[2 * q + 1] += hi.f;
        }
    }
    float4* o = (float4*)(out + (size_t)j * 8);
    o[0] = make_float4(s[0], s[1], s[2], s[3]);
    o[1] = make_float4(s[4], s[5], s[6], s[7]);
}

extern "C" void kernel_launch(void* const* d_in, const int* in_sizes, int n_in,
                              void* d_out, int out_size, void* d_ws, size_t ws_size,
                              hipStream_t stream) {
    const float* weight   = (const float*)d_in[0];
    const float* pre_s    = (const float*)d_in[1];
    const float* post_s   = (const float*)d_in[2];
    const float* pre_tr0  = (const float*)d_in[3];
    const float* post_tr0 = (const float*)d_in[4];
    float* out = (float*)d_out;

    uchar* wsb = (uchar*)d_ws;
    uchar* pre_s_t   = wsb + B_PRST;
    uchar* pre_tr_t  = wsb + B_PRTT;
    uchar* post_s_t  = wsb + B_POST;
    uchar* post_tr_t = wsb + B_POTT;
    ushort* Spart    = (ushort*)(wsb + B_END);

    stdp_traces_t<<<dim3(BATCH * (NIN + NOUT) / 64), dim3(256), 0, stream>>>(
        pre_s, post_s, pre_tr0, post_tr0,
        pre_s_t, pre_tr_t, post_s_t, post_tr_t, out);

    stdp_gemm_dual<<<dim3(KS, NIN / 64, NOUT / 128), dim3(256), 0, stream>>>(
        post_s_t, pre_tr_t, post_tr_t, pre_s_t, weight, Spart);

    stdp_finalize<<<dim3((NOUT * NIN / 8) / 128), dim3(128), 0, stream>>>(
        Spart, out);
}